// Round 1
// baseline (1174.055 us; speedup 1.0000x reference)
//
#include <hip/hip_runtime.h>

// PersistentMemory: x[16384,1024], bank[8192,1024]; all fp32 in/out.
// Round 4: attention re-chunked over the BANK dim (8 slices of 1024) so both
// the S-exp GEMM and the PV GEMM are M=16384,N=1024,K=1024 shapes with
// grid 8x128 = 1024 blocks (3 blocks/CU) using the proven gemm_bb structure.
// The old pv_gemm (M=4096,N=1024,K=8192 -> 256 blocks = 1/CU, 597 TF, MfmaUtil
// 24%) is retired on the big path. P_c (32 MB) and Racc (32 MB) split d_out;
// retrieved is normalized by L into the dead Kb+Vt region before the concat.
// Base ws need: 64 MB + 64 KB. If ws >= 123 MB, inputs are pre-converted to
// bf16 and all GEMMs use the m97 global_load_lds structure (big path).

typedef __bf16 bf16;
typedef __bf16 bf16x4 __attribute__((ext_vector_type(4)));
typedef __bf16 bf16x8 __attribute__((ext_vector_type(8)));
typedef float f32x4 __attribute__((ext_vector_type(4)));

static __device__ __forceinline__ f32x4 mfma16(bf16x8 a, bf16x8 b, f32x4 c) {
  return __builtin_amdgcn_mfma_f32_16x16x32_bf16(a, b, c, 0, 0, 0);
}

// async global->LDS, 16B per lane; LDS dest = wave-uniform base + lane*16
#define GLDS16(gp, lp) __builtin_amdgcn_global_load_lds( \
    (const __attribute__((address_space(1))) void*)(gp), \
    (__attribute__((address_space(3))) void*)(lp), 16, 0, 0)

// ---------------------------------------------------------------------------
// bf16 NT-GEMM, m97 structure: C[M,N]=A[M,K]@W[N,K]^T (W row stride = ldw).
// 128x128 tile, BK=64, 256 thr = 4 waves (2x2, wave tile 64x64). Staging:
// global_load_lds width 16, XOR column-group swizzle (applied on the per-lane
// GLOBAL address) so frag ds_read_b128 hits the LDS bank floor.
// EPI 0: C = bf16(acc + bias[col])                       (Q, K GEMMs)
// EPI 1: C = bf16(acc + bias[row])                       (Vt GEMM)
// EPI 2: C = bf16(exp(acc/32)), rowsum atomicAdd -> L    (S-exp)
// EPI 3: C = f32(acc + bias[col] + resid[row,col])       (concat GEMM)
// EPI 4: C = bf16(acc)                                   (PV chunk 0)
// EPI 5: C = bf16(acc + Cprev) where Cprev=(bf16*)resid  (PV chunks 1..7, RMW)
// CONCAT: A columns >=1024 come from A2 (both stride 1024).
// ---------------------------------------------------------------------------
template<int EPI, int CONCAT>
__global__ __launch_bounds__(256, 3) void gemm_bb(
    const bf16* __restrict__ A, const bf16* __restrict__ A2,
    const bf16* __restrict__ W, const float* __restrict__ bias,
    const float* __restrict__ resid, float* __restrict__ L,
    void* __restrict__ Cout, int N, int K, int ldw)
{
  __shared__ bf16 As[128 * 64];
  __shared__ bf16 Bs[128 * 64];
  const int tid = threadIdx.x, lane = tid & 63, wid = tid >> 6;
  const int wm = (wid >> 1) * 64, wn = (wid & 1) * 64;
  const int quad = lane >> 4, l16 = lane & 15;
  const long bm = (long)blockIdx.y * 128, bn = (long)blockIdx.x * 128;

  int prow[4], pcg[4];
#pragma unroll
  for (int i = 0; i < 4; ++i) {
    int p = ((wid * 4 + i) << 6) + lane;   // 16B slot index in [0,1024)
    prow[i] = p >> 3;                      // 8 slots per 64-elem row
    pcg[i] = (p & 7) ^ (prow[i] & 7);
  }

  f32x4 acc[4][4] = {};

  for (int k0 = 0; k0 < K; k0 += 64) {
    const bf16* Asrc = (CONCAT && k0 >= 1024) ? A2 : A;
    const int kA = (CONCAT && k0 >= 1024) ? k0 - 1024 : k0;
    const int lda = CONCAT ? 1024 : K;
    __syncthreads();   // previous iteration's frag reads done before overwrite
#pragma unroll
    for (int i = 0; i < 4; ++i) {
      const bf16* ga = Asrc + (size_t)(bm + prow[i]) * lda + kA + pcg[i] * 8;
      GLDS16(ga, (char*)As + ((wid * 4 + i) << 10));
    }
#pragma unroll
    for (int i = 0; i < 4; ++i) {
      const bf16* gb = W + (size_t)(bn + prow[i]) * ldw + k0 + pcg[i] * 8;
      GLDS16(gb, (char*)Bs + ((wid * 4 + i) << 10));
    }
    __syncthreads();   // staging complete (vmcnt drained before barrier)
#pragma unroll
    for (int kk = 0; kk < 2; ++kk) {
      bf16x8 af[4], bfv[4];
#pragma unroll
      for (int mt = 0; mt < 4; ++mt) {
        const int r = wm + mt * 16 + l16;
        af[mt] = *(const bf16x8*)((const char*)As + (r << 7)
                                  + ((((kk << 2) + quad) ^ (r & 7)) << 4));
      }
#pragma unroll
      for (int nt = 0; nt < 4; ++nt) {
        const int r = wn + nt * 16 + l16;
        bfv[nt] = *(const bf16x8*)((const char*)Bs + (r << 7)
                                   + ((((kk << 2) + quad) ^ (r & 7)) << 4));
      }
#pragma unroll
      for (int mt = 0; mt < 4; ++mt)
#pragma unroll
        for (int nt = 0; nt < 4; ++nt)
          acc[mt][nt] = mfma16(af[mt], bfv[nt], acc[mt][nt]);
    }
  }

#pragma unroll
  for (int mt = 0; mt < 4; ++mt) {
    const long row0 = bm + wm + mt * 16 + quad * 4;
    if (EPI == 2) {
      float rsum[4] = {0.f, 0.f, 0.f, 0.f};
#pragma unroll
      for (int nt = 0; nt < 4; ++nt) {
        const long col = bn + wn + nt * 16 + l16;
#pragma unroll
        for (int r = 0; r < 4; ++r) {
          float p = __expf(acc[mt][nt][r] * 0.03125f);
          rsum[r] += p;
          ((bf16*)Cout)[(size_t)(row0 + r) * N + col] = (bf16)p;
        }
      }
#pragma unroll
      for (int s = 1; s < 16; s <<= 1)
#pragma unroll
        for (int r = 0; r < 4; ++r) rsum[r] += __shfl_xor(rsum[r], s, 64);
      if (l16 == 0) {
#pragma unroll
        for (int r = 0; r < 4; ++r) atomicAdd(&L[row0 + r], rsum[r]);
      }
    } else if (EPI == 4 || EPI == 5) {
#pragma unroll
      for (int nt = 0; nt < 4; ++nt) {
        const long col = bn + wn + nt * 16 + l16;
#pragma unroll
        for (int r = 0; r < 4; ++r) {
          float v = acc[mt][nt][r];
          if (EPI == 5)
            v += (float)((const bf16*)resid)[(size_t)(row0 + r) * N + col];
          ((bf16*)Cout)[(size_t)(row0 + r) * N + col] = (bf16)v;
        }
      }
    } else {
#pragma unroll
      for (int nt = 0; nt < 4; ++nt) {
        const long col = bn + wn + nt * 16 + l16;
        const float bc = (EPI == 1) ? 0.f : bias[col];
#pragma unroll
        for (int r = 0; r < 4; ++r) {
          float v = acc[mt][nt][r] + ((EPI == 1) ? bias[row0 + r] : bc);
          if (EPI == 3) {
            v += resid[(size_t)(row0 + r) * 1024 + col];
            ((float*)Cout)[(size_t)(row0 + r) * N + col] = v;
          } else {
            ((bf16*)Cout)[(size_t)(row0 + r) * N + col] = (bf16)v;
          }
        }
      }
    }
  }
}

// ---------------------------------------------------------------------------
// PV GEMM for the small-ws fallback path only (M-chunked attention).
// Rb[M,1024] = (P[M,8192] @ Vt[1024,8192]^T) / L[row].  512 thr = 8 waves,
// 128x128 tile, BK=128.
// ---------------------------------------------------------------------------
__global__ __launch_bounds__(512, 2) void pv_gemm(
    const bf16* __restrict__ P, const bf16* __restrict__ Vt,
    const float* __restrict__ L, bf16* __restrict__ Rb)
{
  __shared__ bf16 As[128 * 128];
  __shared__ bf16 Bs[128 * 128];
  const int tid = threadIdx.x, lane = tid & 63, wid = tid >> 6;
  const int wm = (wid & 3) * 32, wn = (wid >> 2) * 64;
  const int quad = lane >> 4, l16 = lane & 15;
  const long bm = (long)blockIdx.y * 128, bn = (long)blockIdx.x * 128;

  int prow[4], pcg[4];
#pragma unroll
  for (int i = 0; i < 4; ++i) {
    int p = ((wid * 4 + i) << 6) + lane;   // 16B slot in [0,2048)
    prow[i] = p >> 4;                      // 16 slots per 128-elem row
    pcg[i] = (p & 15) ^ (prow[i] & 15);
  }

  f32x4 acc[2][4] = {};

  for (int k0 = 0; k0 < 8192; k0 += 128) {
    __syncthreads();
#pragma unroll
    for (int i = 0; i < 4; ++i)
      GLDS16(P + (size_t)(bm + prow[i]) * 8192 + k0 + pcg[i] * 8,
             (char*)As + ((wid * 4 + i) << 10));
#pragma unroll
    for (int i = 0; i < 4; ++i)
      GLDS16(Vt + (size_t)(bn + prow[i]) * 8192 + k0 + pcg[i] * 8,
             (char*)Bs + ((wid * 4 + i) << 10));
    __syncthreads();
#pragma unroll
    for (int kk = 0; kk < 4; ++kk) {
      bf16x8 af[2], bfv[4];
#pragma unroll
      for (int mt = 0; mt < 2; ++mt) {
        const int r = wm + mt * 16 + l16;
        af[mt] = *(const bf16x8*)((const char*)As + (r << 8)
                                  + ((((kk << 2) + quad) ^ (r & 15)) << 4));
      }
#pragma unroll
      for (int nt = 0; nt < 4; ++nt) {
        const int r = wn + nt * 16 + l16;
        bfv[nt] = *(const bf16x8*)((const char*)Bs + (r << 8)
                                   + ((((kk << 2) + quad) ^ (r & 15)) << 4));
      }
#pragma unroll
      for (int mt = 0; mt < 2; ++mt)
#pragma unroll
        for (int nt = 0; nt < 4; ++nt)
          acc[mt][nt] = mfma16(af[mt], bfv[nt], acc[mt][nt]);
    }
  }

#pragma unroll
  for (int mt = 0; mt < 2; ++mt) {
    const long row0 = bm + wm + mt * 16 + quad * 4;
    float linv[4];
#pragma unroll
    for (int r = 0; r < 4; ++r) linv[r] = 1.f / L[row0 + r];
#pragma unroll
    for (int nt = 0; nt < 4; ++nt) {
      const long col = bn + wn + nt * 16 + l16;
#pragma unroll
      for (int r = 0; r < 4; ++r)
        Rb[(size_t)(row0 + r) * 1024 + col] = (bf16)(acc[mt][nt][r] * linv[r]);
    }
  }
}

// ---------------------------------------------------------------------------
// fp32-input NT-GEMM (small-ws path only): C[M,N] = A[M,K] @ W[N,K]^T (+bias).
// ---------------------------------------------------------------------------
template<int BIAS_ROW, int OUT_F32_RES, int CONCAT>
__global__ __launch_bounds__(256, 3) void gemm_nt(
    const float* __restrict__ A, const bf16* __restrict__ A2,
    const float* __restrict__ W, const float* __restrict__ bias,
    const float* __restrict__ resid, void* __restrict__ Cout,
    int M, int N, int K)
{
  __shared__ bf16 As[128][72];
  __shared__ bf16 Bs[128][72];
  const int tid  = threadIdx.x;
  const int lane = tid & 63;
  const int wid  = tid >> 6;
  const int wm   = (wid >> 1) * 64, wn = (wid & 1) * 64;
  const int quad = lane >> 4, l16 = lane & 15;
  const long bm = (long)blockIdx.y * 128, bn = (long)blockIdx.x * 128;
  const int r0 = tid >> 2, cq = (tid & 3) * 16;
  const int lda = CONCAT ? 1024 : K;

  f32x4 acc[4][4] = {};

  for (int k0 = 0; k0 < K; k0 += 64) {
    const bool useb = CONCAT && (k0 >= 1024);
    const int kA = useb ? (k0 - 1024) : k0;
    f32x4 va[2][4], vb[2][4];
    bf16x8 ra[2][2];
    if (useb) {
#pragma unroll
      for (int g = 0; g < 2; ++g) {
        const bf16* p = A2 + (size_t)(bm + r0 + 64 * g) * 1024 + kA + cq;
        ra[g][0] = *(const bf16x8*)p;
        ra[g][1] = *(const bf16x8*)(p + 8);
      }
    } else {
#pragma unroll
      for (int g = 0; g < 2; ++g) {
        const f32x4* p = (const f32x4*)(A + (size_t)(bm + r0 + 64 * g) * lda + kA + cq);
#pragma unroll
        for (int j = 0; j < 4; ++j) va[g][j] = p[j];
      }
    }
#pragma unroll
    for (int g = 0; g < 2; ++g) {
      const f32x4* p = (const f32x4*)(W + (size_t)(bn + r0 + 64 * g) * K + k0 + cq);
#pragma unroll
      for (int j = 0; j < 4; ++j) vb[g][j] = p[j];
    }
    __syncthreads();
#pragma unroll
    for (int g = 0; g < 2; ++g) {
      bf16* dA = &As[r0 + 64 * g][cq];
      if (useb) {
        *(bf16x8*)dA = ra[g][0]; *(bf16x8*)(dA + 8) = ra[g][1];
      } else {
        bf16x8 t0, t1;
#pragma unroll
        for (int j = 0; j < 4; ++j) {
          t0[j] = (bf16)va[g][0][j]; t0[4 + j] = (bf16)va[g][1][j];
          t1[j] = (bf16)va[g][2][j]; t1[4 + j] = (bf16)va[g][3][j];
        }
        *(bf16x8*)dA = t0; *(bf16x8*)(dA + 8) = t1;
      }
      bf16* dB = &Bs[r0 + 64 * g][cq];
      bf16x8 u0, u1;
#pragma unroll
      for (int j = 0; j < 4; ++j) {
        u0[j] = (bf16)vb[g][0][j]; u0[4 + j] = (bf16)vb[g][1][j];
        u1[j] = (bf16)vb[g][2][j]; u1[4 + j] = (bf16)vb[g][3][j];
      }
      *(bf16x8*)dB = u0; *(bf16x8*)(dB + 8) = u1;
    }
    __syncthreads();
#pragma unroll
    for (int kk = 0; kk < 2; ++kk) {
      bf16x8 af[4], bfv[4];
#pragma unroll
      for (int mt = 0; mt < 4; ++mt)
        af[mt] = *(const bf16x8*)&As[wm + mt * 16 + l16][kk * 32 + quad * 8];
#pragma unroll
      for (int nt = 0; nt < 4; ++nt)
        bfv[nt] = *(const bf16x8*)&Bs[wn + nt * 16 + l16][kk * 32 + quad * 8];
#pragma unroll
      for (int mt = 0; mt < 4; ++mt)
#pragma unroll
        for (int nt = 0; nt < 4; ++nt)
          acc[mt][nt] = mfma16(af[mt], bfv[nt], acc[mt][nt]);
    }
  }
#pragma unroll
  for (int mt = 0; mt < 4; ++mt) {
    const long row0 = bm + wm + mt * 16 + quad * 4;
#pragma unroll
    for (int nt = 0; nt < 4; ++nt) {
      const long col = bn + wn + nt * 16 + l16;
      const float bc = BIAS_ROW ? 0.f : bias[col];
#pragma unroll
      for (int r = 0; r < 4; ++r) {
        float v = acc[mt][nt][r] + (BIAS_ROW ? bias[row0 + r] : bc);
        if (OUT_F32_RES) {
          v += resid[(size_t)(row0 + r) * 1024 + col];
          ((float*)Cout)[(size_t)(row0 + r) * N + col] = v;
        } else {
          ((bf16*)Cout)[(size_t)(row0 + r) * N + col] = (bf16)v;
        }
      }
    }
  }
}

// ---------------------------------------------------------------------------
// fp32 -> bf16 bulk convert of the six read-only inputs (big-ws path).
// One f32x4 per thread; segment bounds in float4 units.
// ---------------------------------------------------------------------------
__global__ __launch_bounds__(256) void cvt6(
    const float* __restrict__ x, const float* __restrict__ bank,
    const float* __restrict__ wq, const float* __restrict__ wk,
    const float* __restrict__ wv, const float* __restrict__ wf,
    bf16* __restrict__ xb, bf16* __restrict__ bankb,
    bf16* __restrict__ wqb, bf16* __restrict__ wkb,
    bf16* __restrict__ wvb, bf16* __restrict__ wfb)
{
  long i4 = (long)blockIdx.x * 256 + threadIdx.x;
  const float* src; bf16* dst; long off;
  if      (i4 < 4194304) { src = x;    dst = xb;    off = i4; }
  else if (i4 < 6291456) { src = bank; dst = bankb; off = i4 - 4194304; }
  else if (i4 < 6553600) { src = wq;   dst = wqb;   off = i4 - 6291456; }
  else if (i4 < 6815744) { src = wk;   dst = wkb;   off = i4 - 6553600; }
  else if (i4 < 7077888) { src = wv;   dst = wvb;   off = i4 - 6815744; }
  else if (i4 < 7602176) { src = wf;   dst = wfb;   off = i4 - 7077888; }
  else return;
  f32x4 v = ((const f32x4*)src)[off];
  bf16x4 o;
#pragma unroll
  for (int j = 0; j < 4; ++j) o[j] = (bf16)v[j];
  ((bf16x4*)dst)[off] = o;
}

__global__ __launch_bounds__(256) void zerof(float* __restrict__ p) {
  p[(size_t)blockIdx.x * 256 + threadIdx.x] = 0.f;
}

// ---------------------------------------------------------------------------
// Normalize retrieved: Rout[row,:] = Racc[row,:] / L[row].  One block per row,
// 256 thr x 4 bf16. Runs after the last PV chunk (Kb/Vt region is dead).
// ---------------------------------------------------------------------------
__global__ __launch_bounds__(256) void pv_norm(
    const bf16* __restrict__ Racc, const float* __restrict__ L,
    bf16* __restrict__ Rout)
{
  const size_t row = blockIdx.x;
  const float linv = 1.f / L[row];
  const int t = threadIdx.x;
  bf16x4 v = ((const bf16x4*)(Racc + row * 1024))[t];
  bf16x4 o;
#pragma unroll
  for (int j = 0; j < 4; ++j) o[j] = (bf16)((float)v[j] * linv);
  ((bf16x4*)(Rout + row * 1024))[t] = o;
}

// ---------------------------------------------------------------------------
// In-place LayerNorm over last dim (1024). One block per row, 256 threads x4.
// ---------------------------------------------------------------------------
__global__ __launch_bounds__(256) void ln_kernel(
    float* __restrict__ h, const float* __restrict__ g, const float* __restrict__ b)
{
  const int tid = threadIdx.x;
  const size_t row = blockIdx.x;
  f32x4 v = *(f32x4*)&h[row * 1024 + tid * 4];
  float s1 = v[0] + v[1] + v[2] + v[3];
  float s2 = v[0]*v[0] + v[1]*v[1] + v[2]*v[2] + v[3]*v[3];
#pragma unroll
  for (int d = 1; d < 64; d <<= 1) { s1 += __shfl_xor(s1, d, 64); s2 += __shfl_xor(s2, d, 64); }
  __shared__ float a1[4], a2[4];
  const int wid = tid >> 6;
  if ((tid & 63) == 0) { a1[wid] = s1; a2[wid] = s2; }
  __syncthreads();
  s1 = a1[0] + a1[1] + a1[2] + a1[3];
  s2 = a2[0] + a2[1] + a2[2] + a2[3];
  const float mu = s1 * (1.f / 1024.f);
  const float rs = rsqrtf(s2 * (1.f / 1024.f) - mu * mu + 1e-5f);
  f32x4 gv = *(const f32x4*)&g[tid * 4];
  f32x4 bv = *(const f32x4*)&b[tid * 4];
#pragma unroll
  for (int j = 0; j < 4; ++j) v[j] = (v[j] - mu) * rs * gv[j] + bv[j];
  *(f32x4*)&h[row * 1024 + tid * 4] = v;
}

// ---------------------------------------------------------------------------
extern "C" void kernel_launch(void* const* d_in, const int* in_sizes, int n_in,
                              void* d_out, int out_size, void* d_ws, size_t ws_size,
                              hipStream_t stream)
{
  const float* x     = (const float*)d_in[0];
  const float* kbank = (const float*)d_in[1];
  const float* wq    = (const float*)d_in[2];
  const float* bq    = (const float*)d_in[3];
  const float* wk    = (const float*)d_in[4];
  const float* bk    = (const float*)d_in[5];
  const float* wv    = (const float*)d_in[6];
  const float* bv    = (const float*)d_in[7];
  const float* wf    = (const float*)d_in[8];
  const float* bf_   = (const float*)d_in[9];
  const float* gamma = (const float*)d_in[10];
  const float* beta  = (const float*)d_in[11];

  // ws layout (MB offsets):
  //   [0,32)   Qb bf16[16384,1024]   (alive through all S-exp chunks)
  //   [32,48)  Kb bf16[8192,1024]    (dead after S-exp chunk 7)
  //   [48,64)  Vt bf16[1024,8192]    (dead after PV chunk 7)
  //   [32,64)  Rfin bf16[16384,1024] (big path; written by pv_norm over Kb+Vt)
  //   [64,+64K) L f32[16384]
  //   big path (ws >= 123 MB):
  //   [65,97)  xb   [97,113) bankb  [113,117) wfb  [117,119) wqb
  //   [119,121) wkb [121,123) wvb
  // d_out (64 MB), big path: [0,32) P_c bf16[16384,1024] per bank-chunk,
  //   [32,64) Racc bf16[16384,1024]; both dead before the concat GEMM writes
  //   the fp32 output over the full 64 MB.
  char* ws = (char*)d_ws;
  const size_t MB = 1024 * 1024;
  bf16*  Qb    = (bf16*)ws;
  bf16*  Rb    = Qb;                       // small path alias: PV after S-exp
  bf16*  Kb    = (bf16*)(ws + 32 * MB);
  bf16*  Vt    = (bf16*)(ws + 48 * MB);
  bf16*  Rfin  = (bf16*)(ws + 32 * MB);    // big path: over dead Kb+Vt
  float* L     = (float*)(ws + 64 * MB);
  bf16*  xb    = (bf16*)(ws + 65 * MB);
  bf16*  bankb = (bf16*)(ws + 97 * MB);
  bf16*  wfb   = (bf16*)(ws + 113 * MB);
  bf16*  wqb   = (bf16*)(ws + 117 * MB);
  bf16*  wkb   = (bf16*)(ws + 119 * MB);
  bf16*  wvb   = (bf16*)(ws + 121 * MB);
  bf16*  P     = (bf16*)d_out;
  bf16*  Racc  = (bf16*)((char*)d_out + 32 * MB);
  float* out   = (float*)d_out;
  const bool big = ws_size >= 123 * MB;

  if (big) {
    cvt6<<<dim3(29696), dim3(256), 0, stream>>>(
        x, kbank, wq, wk, wv, wf, xb, bankb, wqb, wkb, wvb, wfb);
    gemm_bb<0,0><<<dim3(8, 128), dim3(256), 0, stream>>>(
        xb, nullptr, wqb, bq, nullptr, nullptr, (void*)Qb, 1024, 1024, 1024);
    gemm_bb<0,0><<<dim3(8, 64), dim3(256), 0, stream>>>(
        bankb, nullptr, wkb, bk, nullptr, nullptr, (void*)Kb, 1024, 1024, 1024);
    gemm_bb<1,0><<<dim3(64, 8), dim3(256), 0, stream>>>(
        wvb, nullptr, bankb, bv, nullptr, nullptr, (void*)Vt, 8192, 1024, 1024);
    zerof<<<dim3(64), dim3(256), 0, stream>>>(L);

    // Attention chunked over the bank dim: 8 slices of 1024 entries.
    for (int c = 0; c < 8; ++c) {
      // P = exp(Q @ K_c^T / 32) into d_out[0,32MB); rowsums accumulate -> L
      gemm_bb<2,0><<<dim3(8, 128), dim3(256), 0, stream>>>(
          Qb, nullptr, Kb + (size_t)c * 1024 * 1024, nullptr, nullptr,
          L, (void*)P, 1024, 1024, 1024);
      // Racc += P @ Vt[:, c*1024 : c*1024+1024]^T   (bf16 RMW accumulate)
      if (c == 0)
        gemm_bb<4,0><<<dim3(8, 128), dim3(256), 0, stream>>>(
            P, nullptr, Vt + (size_t)c * 1024, nullptr, nullptr, nullptr,
            (void*)Racc, 1024, 1024, 8192);
      else
        gemm_bb<5,0><<<dim3(8, 128), dim3(256), 0, stream>>>(
            P, nullptr, Vt + (size_t)c * 1024, nullptr, (const float*)Racc,
            nullptr, (void*)Racc, 1024, 1024, 8192);
    }
    // Rfin = Racc / L  (over dead Kb+Vt; frees d_out for the concat output)
    pv_norm<<<dim3(16384), dim3(256), 0, stream>>>(Racc, L, Rfin);

    // h = [x, retrieved] @ wf^T + bf + x -> d_out (fp32)
    gemm_bb<3,1><<<dim3(8, 128), dim3(256), 0, stream>>>(
        xb, Rfin, wfb, bf_, x, nullptr, (void*)out, 1024, 2048, 2048);
  } else {
    // Small-ws fallback: original M-chunked flow (P chunk in d_out, Rb=Qb).
    gemm_nt<0,0,0><<<dim3(8, 128), dim3(256), 0, stream>>>(
        x, nullptr, wq, bq, nullptr, (void*)Qb, 16384, 1024, 1024);
    gemm_nt<0,0,0><<<dim3(8, 64), dim3(256), 0, stream>>>(
        kbank, nullptr, wk, bk, nullptr, (void*)Kb, 8192, 1024, 1024);
    gemm_nt<1,0,0><<<dim3(64, 8), dim3(256), 0, stream>>>(
        wv, nullptr, kbank, bv, nullptr, (void*)Vt, 1024, 8192, 1024);
    zerof<<<dim3(64), dim3(256), 0, stream>>>(L);
    for (int c = 0; c < 4; ++c) {
      gemm_bb<2,0><<<dim3(64, 32), dim3(256), 0, stream>>>(
          Qb + (size_t)c * 4096 * 1024, nullptr, Kb, nullptr, nullptr,
          L + c * 4096, (void*)P, 8192, 1024, 1024);
      pv_gemm<<<dim3(8, 32), dim3(512), 0, stream>>>(
          P, Vt, L + c * 4096, Rb + (size_t)c * 4096 * 1024);
    }
    gemm_nt<0,1,1><<<dim3(8, 128), dim3(256), 0, stream>>>(
        x, Rb, wf, bf_, x, (void*)out, 16384, 1024, 2048);
  }
  ln_kernel<<<dim3(16384), dim3(256), 0, stream>>>(out, gamma, beta);
}

// Round 2
// 1086.960 us; speedup vs baseline: 1.0801x; 1.0801x over previous
//
#include <hip/hip_runtime.h>

// PersistentMemory: x[16384,1024], bank[8192,1024]; all fp32 in/out.
// Round 5: revert to M-chunked attention (round-3 flow: no Racc RMW traffic),
// add (a) T1 XCD-chunked blockIdx swizzle to all MFMA GEMMs (panel re-reads
// were round-robining across the 8 private L2s: concat FETCH 300MB vs 164MB
// unique), and (b) a 2-phase double-buffered pipeline (T3-min) + setprio in
// pv_gemm, which runs at 1 block/CU where the stage+drain latency of the
// 2-barrier loop is fully exposed (MfmaUtil 24%).
// Base ws need: 64 MB + 64 KB. If ws >= 123 MB, inputs are pre-converted to
// bf16 and all GEMMs use the m97 global_load_lds structure (big path).

typedef __bf16 bf16;
typedef __bf16 bf16x4 __attribute__((ext_vector_type(4)));
typedef __bf16 bf16x8 __attribute__((ext_vector_type(8)));
typedef float f32x4 __attribute__((ext_vector_type(4)));

static __device__ __forceinline__ f32x4 mfma16(bf16x8 a, bf16x8 b, f32x4 c) {
  return __builtin_amdgcn_mfma_f32_16x16x32_bf16(a, b, c, 0, 0, 0);
}

// async global->LDS, 16B per lane; LDS dest = wave-uniform base + lane*16
#define GLDS16(gp, lp) __builtin_amdgcn_global_load_lds( \
    (const __attribute__((address_space(1))) void*)(gp), \
    (__attribute__((address_space(3))) void*)(lp), 16, 0, 0)

// XCD-chunked bijective swizzle; requires nwg % 8 == 0 (all grids here are).
// Dispatch round-robins flat id across the 8 XCDs; this remap gives each XCD
// a contiguous chunk of work ids so blocks sharing an A/B panel share an L2.
static __device__ __forceinline__ void xcd_swizzle(long& bm, long& bn) {
  const int nwg = (int)(gridDim.x * gridDim.y);
  int flat = (int)(blockIdx.y * gridDim.x + blockIdx.x);
  flat = (flat & 7) * (nwg >> 3) + (flat >> 3);
  bm = (long)(flat / (int)gridDim.x) * 128;
  bn = (long)(flat % (int)gridDim.x) * 128;
}

// ---------------------------------------------------------------------------
// bf16 NT-GEMM, m97 structure: C[M,N]=A[M,K]@W[N,K]^T (W row stride = ldw).
// 128x128 tile, BK=64, 256 thr = 4 waves (2x2, wave tile 64x64). Staging:
// global_load_lds width 16, XOR column-group swizzle (applied on the per-lane
// GLOBAL address) so frag ds_read_b128 hits the LDS bank floor.
// EPI 0: C = bf16(acc + bias[col])                       (Q, K GEMMs)
// EPI 1: C = bf16(acc + bias[row])                       (Vt GEMM)
// EPI 2: C = bf16(exp(acc/32)), rowsum atomicAdd -> L    (S-exp)
// EPI 3: C = f32(acc + bias[col] + resid[row,col])       (concat GEMM)
// CONCAT: A columns >=1024 come from A2 (both stride 1024).
// ---------------------------------------------------------------------------
template<int EPI, int CONCAT>
__global__ __launch_bounds__(256, 3) void gemm_bb(
    const bf16* __restrict__ A, const bf16* __restrict__ A2,
    const bf16* __restrict__ W, const float* __restrict__ bias,
    const float* __restrict__ resid, float* __restrict__ L,
    void* __restrict__ Cout, int N, int K, int ldw)
{
  __shared__ bf16 As[128 * 64];
  __shared__ bf16 Bs[128 * 64];
  const int tid = threadIdx.x, lane = tid & 63, wid = tid >> 6;
  const int wm = (wid >> 1) * 64, wn = (wid & 1) * 64;
  const int quad = lane >> 4, l16 = lane & 15;
  long bm, bn;
  xcd_swizzle(bm, bn);

  int prow[4], pcg[4];
#pragma unroll
  for (int i = 0; i < 4; ++i) {
    int p = ((wid * 4 + i) << 6) + lane;   // 16B slot index in [0,1024)
    prow[i] = p >> 3;                      // 8 slots per 64-elem row
    pcg[i] = (p & 7) ^ (prow[i] & 7);
  }

  f32x4 acc[4][4] = {};

  for (int k0 = 0; k0 < K; k0 += 64) {
    const bf16* Asrc = (CONCAT && k0 >= 1024) ? A2 : A;
    const int kA = (CONCAT && k0 >= 1024) ? k0 - 1024 : k0;
    const int lda = CONCAT ? 1024 : K;
    __syncthreads();   // previous iteration's frag reads done before overwrite
#pragma unroll
    for (int i = 0; i < 4; ++i) {
      const bf16* ga = Asrc + (size_t)(bm + prow[i]) * lda + kA + pcg[i] * 8;
      GLDS16(ga, (char*)As + ((wid * 4 + i) << 10));
    }
#pragma unroll
    for (int i = 0; i < 4; ++i) {
      const bf16* gb = W + (size_t)(bn + prow[i]) * ldw + k0 + pcg[i] * 8;
      GLDS16(gb, (char*)Bs + ((wid * 4 + i) << 10));
    }
    __syncthreads();   // staging complete (vmcnt drained before barrier)
#pragma unroll
    for (int kk = 0; kk < 2; ++kk) {
      bf16x8 af[4], bfv[4];
#pragma unroll
      for (int mt = 0; mt < 4; ++mt) {
        const int r = wm + mt * 16 + l16;
        af[mt] = *(const bf16x8*)((const char*)As + (r << 7)
                                  + ((((kk << 2) + quad) ^ (r & 7)) << 4));
      }
#pragma unroll
      for (int nt = 0; nt < 4; ++nt) {
        const int r = wn + nt * 16 + l16;
        bfv[nt] = *(const bf16x8*)((const char*)Bs + (r << 7)
                                   + ((((kk << 2) + quad) ^ (r & 7)) << 4));
      }
#pragma unroll
      for (int mt = 0; mt < 4; ++mt)
#pragma unroll
        for (int nt = 0; nt < 4; ++nt)
          acc[mt][nt] = mfma16(af[mt], bfv[nt], acc[mt][nt]);
    }
  }

#pragma unroll
  for (int mt = 0; mt < 4; ++mt) {
    const long row0 = bm + wm + mt * 16 + quad * 4;
    if (EPI == 2) {
      float rsum[4] = {0.f, 0.f, 0.f, 0.f};
#pragma unroll
      for (int nt = 0; nt < 4; ++nt) {
        const long col = bn + wn + nt * 16 + l16;
#pragma unroll
        for (int r = 0; r < 4; ++r) {
          float p = __expf(acc[mt][nt][r] * 0.03125f);
          rsum[r] += p;
          ((bf16*)Cout)[(size_t)(row0 + r) * N + col] = (bf16)p;
        }
      }
#pragma unroll
      for (int s = 1; s < 16; s <<= 1)
#pragma unroll
        for (int r = 0; r < 4; ++r) rsum[r] += __shfl_xor(rsum[r], s, 64);
      if (l16 == 0) {
#pragma unroll
        for (int r = 0; r < 4; ++r) atomicAdd(&L[row0 + r], rsum[r]);
      }
    } else {
#pragma unroll
      for (int nt = 0; nt < 4; ++nt) {
        const long col = bn + wn + nt * 16 + l16;
        const float bc = (EPI == 1) ? 0.f : bias[col];
#pragma unroll
        for (int r = 0; r < 4; ++r) {
          float v = acc[mt][nt][r] + ((EPI == 1) ? bias[row0 + r] : bc);
          if (EPI == 3) {
            v += resid[(size_t)(row0 + r) * 1024 + col];
            ((float*)Cout)[(size_t)(row0 + r) * N + col] = v;
          } else {
            ((bf16*)Cout)[(size_t)(row0 + r) * N + col] = (bf16)v;
          }
        }
      }
    }
  }
}

// ---------------------------------------------------------------------------
// PV GEMM: Rb[4096,1024] = (P[4096,8192] @ Vt[1024,8192]^T) / L[row].
// 512 thr = 8 waves (4m x 2n, wave tile 32x64), 128x128 tile, BK=128.
// Grid 8x32 = 256 blocks = 1 block/CU (128 KB LDS), so the stage latency
// cannot hide behind other blocks -> 2-phase double-buffered pipeline:
// issue next tile's global_load_lds into buf^1 BEFORE computing buf, one
// vmcnt-drain+barrier per K-step (T3-min), setprio(1) around the MFMA cluster.
// ---------------------------------------------------------------------------
__global__ __launch_bounds__(512, 2) void pv_gemm(
    const bf16* __restrict__ P, const bf16* __restrict__ Vt,
    const float* __restrict__ L, bf16* __restrict__ Rb)
{
  __shared__ bf16 As[2][128 * 128];
  __shared__ bf16 Bs[2][128 * 128];
  const int tid = threadIdx.x, lane = tid & 63, wid = tid >> 6;
  const int wm = (wid & 3) * 32, wn = (wid >> 2) * 64;
  const int quad = lane >> 4, l16 = lane & 15;
  long bm, bn;
  xcd_swizzle(bm, bn);

  int prow[4], pcg[4];
#pragma unroll
  for (int i = 0; i < 4; ++i) {
    int p = ((wid * 4 + i) << 6) + lane;   // 16B slot in [0,2048)
    prow[i] = p >> 4;                      // 16 slots per 128-elem row
    pcg[i] = (p & 15) ^ (prow[i] & 15);
  }

  f32x4 acc[2][4] = {};

  auto stage = [&](int buf, int k0) {
#pragma unroll
    for (int i = 0; i < 4; ++i)
      GLDS16(P + (size_t)(bm + prow[i]) * 8192 + k0 + pcg[i] * 8,
             (char*)As[buf] + ((wid * 4 + i) << 10));
#pragma unroll
    for (int i = 0; i < 4; ++i)
      GLDS16(Vt + (size_t)(bn + prow[i]) * 8192 + k0 + pcg[i] * 8,
             (char*)Bs[buf] + ((wid * 4 + i) << 10));
  };

  auto compute = [&](int buf) {
    __builtin_amdgcn_s_setprio(1);
#pragma unroll
    for (int kk = 0; kk < 4; ++kk) {
      bf16x8 af[2], bfv[4];
#pragma unroll
      for (int mt = 0; mt < 2; ++mt) {
        const int r = wm + mt * 16 + l16;
        af[mt] = *(const bf16x8*)((const char*)As[buf] + (r << 8)
                                  + ((((kk << 2) + quad) ^ (r & 15)) << 4));
      }
#pragma unroll
      for (int nt = 0; nt < 4; ++nt) {
        const int r = wn + nt * 16 + l16;
        bfv[nt] = *(const bf16x8*)((const char*)Bs[buf] + (r << 8)
                                   + ((((kk << 2) + quad) ^ (r & 15)) << 4));
      }
#pragma unroll
      for (int mt = 0; mt < 2; ++mt)
#pragma unroll
        for (int nt = 0; nt < 4; ++nt)
          acc[mt][nt] = mfma16(af[mt], bfv[nt], acc[mt][nt]);
    }
    __builtin_amdgcn_s_setprio(0);
  };

  // prologue: fill buffer 0, drain, barrier
  stage(0, 0);
  __syncthreads();
  int cur = 0;
  for (int t = 0; t < 63; ++t) {
    stage(cur ^ 1, (t + 1) * 128);   // next tile's loads fly under compute
    compute(cur);
    __syncthreads();                  // drains vmcnt (stage) + joins waves
    cur ^= 1;
  }
  compute(cur);                       // last tile, no prefetch

#pragma unroll
  for (int mt = 0; mt < 2; ++mt) {
    const long row0 = bm + wm + mt * 16 + quad * 4;
    float linv[4];
#pragma unroll
    for (int r = 0; r < 4; ++r) linv[r] = 1.f / L[row0 + r];
#pragma unroll
    for (int nt = 0; nt < 4; ++nt) {
      const long col = bn + wn + nt * 16 + l16;
#pragma unroll
      for (int r = 0; r < 4; ++r)
        Rb[(size_t)(row0 + r) * 1024 + col] = (bf16)(acc[mt][nt][r] * linv[r]);
    }
  }
}

// ---------------------------------------------------------------------------
// fp32-input NT-GEMM (small-ws path only): C[M,N] = A[M,K] @ W[N,K]^T (+bias).
// ---------------------------------------------------------------------------
template<int BIAS_ROW, int OUT_F32_RES, int CONCAT>
__global__ __launch_bounds__(256, 3) void gemm_nt(
    const float* __restrict__ A, const bf16* __restrict__ A2,
    const float* __restrict__ W, const float* __restrict__ bias,
    const float* __restrict__ resid, void* __restrict__ Cout,
    int M, int N, int K)
{
  __shared__ bf16 As[128][72];
  __shared__ bf16 Bs[128][72];
  const int tid  = threadIdx.x;
  const int lane = tid & 63;
  const int wid  = tid >> 6;
  const int wm   = (wid >> 1) * 64, wn = (wid & 1) * 64;
  const int quad = lane >> 4, l16 = lane & 15;
  const long bm = (long)blockIdx.y * 128, bn = (long)blockIdx.x * 128;
  const int r0 = tid >> 2, cq = (tid & 3) * 16;
  const int lda = CONCAT ? 1024 : K;

  f32x4 acc[4][4] = {};

  for (int k0 = 0; k0 < K; k0 += 64) {
    const bool useb = CONCAT && (k0 >= 1024);
    const int kA = useb ? (k0 - 1024) : k0;
    f32x4 va[2][4], vb[2][4];
    bf16x8 ra[2][2];
    if (useb) {
#pragma unroll
      for (int g = 0; g < 2; ++g) {
        const bf16* p = A2 + (size_t)(bm + r0 + 64 * g) * 1024 + kA + cq;
        ra[g][0] = *(const bf16x8*)p;
        ra[g][1] = *(const bf16x8*)(p + 8);
      }
    } else {
#pragma unroll
      for (int g = 0; g < 2; ++g) {
        const f32x4* p = (const f32x4*)(A + (size_t)(bm + r0 + 64 * g) * lda + kA + cq);
#pragma unroll
        for (int j = 0; j < 4; ++j) va[g][j] = p[j];
      }
    }
#pragma unroll
    for (int g = 0; g < 2; ++g) {
      const f32x4* p = (const f32x4*)(W + (size_t)(bn + r0 + 64 * g) * K + k0 + cq);
#pragma unroll
      for (int j = 0; j < 4; ++j) vb[g][j] = p[j];
    }
    __syncthreads();
#pragma unroll
    for (int g = 0; g < 2; ++g) {
      bf16* dA = &As[r0 + 64 * g][cq];
      if (useb) {
        *(bf16x8*)dA = ra[g][0]; *(bf16x8*)(dA + 8) = ra[g][1];
      } else {
        bf16x8 t0, t1;
#pragma unroll
        for (int j = 0; j < 4; ++j) {
          t0[j] = (bf16)va[g][0][j]; t0[4 + j] = (bf16)va[g][1][j];
          t1[j] = (bf16)va[g][2][j]; t1[4 + j] = (bf16)va[g][3][j];
        }
        *(bf16x8*)dA = t0; *(bf16x8*)(dA + 8) = t1;
      }
      bf16* dB = &Bs[r0 + 64 * g][cq];
      bf16x8 u0, u1;
#pragma unroll
      for (int j = 0; j < 4; ++j) {
        u0[j] = (bf16)vb[g][0][j]; u0[4 + j] = (bf16)vb[g][1][j];
        u1[j] = (bf16)vb[g][2][j]; u1[4 + j] = (bf16)vb[g][3][j];
      }
      *(bf16x8*)dB = u0; *(bf16x8*)(dB + 8) = u1;
    }
    __syncthreads();
#pragma unroll
    for (int kk = 0; kk < 2; ++kk) {
      bf16x8 af[4], bfv[4];
#pragma unroll
      for (int mt = 0; mt < 4; ++mt)
        af[mt] = *(const bf16x8*)&As[wm + mt * 16 + l16][kk * 32 + quad * 8];
#pragma unroll
      for (int nt = 0; nt < 4; ++nt)
        bfv[nt] = *(const bf16x8*)&Bs[wn + nt * 16 + l16][kk * 32 + quad * 8];
#pragma unroll
      for (int mt = 0; mt < 4; ++mt)
#pragma unroll
        for (int nt = 0; nt < 4; ++nt)
          acc[mt][nt] = mfma16(af[mt], bfv[nt], acc[mt][nt]);
    }
  }
#pragma unroll
  for (int mt = 0; mt < 4; ++mt) {
    const long row0 = bm + wm + mt * 16 + quad * 4;
#pragma unroll
    for (int nt = 0; nt < 4; ++nt) {
      const long col = bn + wn + nt * 16 + l16;
      const float bc = BIAS_ROW ? 0.f : bias[col];
#pragma unroll
      for (int r = 0; r < 4; ++r) {
        float v = acc[mt][nt][r] + (BIAS_ROW ? bias[row0 + r] : bc);
        if (OUT_F32_RES) {
          v += resid[(size_t)(row0 + r) * 1024 + col];
          ((float*)Cout)[(size_t)(row0 + r) * N + col] = v;
        } else {
          ((bf16*)Cout)[(size_t)(row0 + r) * N + col] = (bf16)v;
        }
      }
    }
  }
}

// ---------------------------------------------------------------------------
// fp32 -> bf16 bulk convert of the six read-only inputs (big-ws path).
// One f32x4 per thread; segment bounds in float4 units.
// ---------------------------------------------------------------------------
__global__ __launch_bounds__(256) void cvt6(
    const float* __restrict__ x, const float* __restrict__ bank,
    const float* __restrict__ wq, const float* __restrict__ wk,
    const float* __restrict__ wv, const float* __restrict__ wf,
    bf16* __restrict__ xb, bf16* __restrict__ bankb,
    bf16* __restrict__ wqb, bf16* __restrict__ wkb,
    bf16* __restrict__ wvb, bf16* __restrict__ wfb)
{
  long i4 = (long)blockIdx.x * 256 + threadIdx.x;
  const float* src; bf16* dst; long off;
  if      (i4 < 4194304) { src = x;    dst = xb;    off = i4; }
  else if (i4 < 6291456) { src = bank; dst = bankb; off = i4 - 4194304; }
  else if (i4 < 6553600) { src = wq;   dst = wqb;   off = i4 - 6291456; }
  else if (i4 < 6815744) { src = wk;   dst = wkb;   off = i4 - 6553600; }
  else if (i4 < 7077888) { src = wv;   dst = wvb;   off = i4 - 6815744; }
  else if (i4 < 7602176) { src = wf;   dst = wfb;   off = i4 - 7077888; }
  else return;
  f32x4 v = ((const f32x4*)src)[off];
  bf16x4 o;
#pragma unroll
  for (int j = 0; j < 4; ++j) o[j] = (bf16)v[j];
  ((bf16x4*)dst)[off] = o;
}

__global__ __launch_bounds__(256) void zerof(float* __restrict__ p) {
  p[(size_t)blockIdx.x * 256 + threadIdx.x] = 0.f;
}

// ---------------------------------------------------------------------------
// In-place LayerNorm over last dim (1024). One block per row, 256 threads x4.
// ---------------------------------------------------------------------------
__global__ __launch_bounds__(256) void ln_kernel(
    float* __restrict__ h, const float* __restrict__ g, const float* __restrict__ b)
{
  const int tid = threadIdx.x;
  const size_t row = blockIdx.x;
  f32x4 v = *(f32x4*)&h[row * 1024 + tid * 4];
  float s1 = v[0] + v[1] + v[2] + v[3];
  float s2 = v[0]*v[0] + v[1]*v[1] + v[2]*v[2] + v[3]*v[3];
#pragma unroll
  for (int d = 1; d < 64; d <<= 1) { s1 += __shfl_xor(s1, d, 64); s2 += __shfl_xor(s2, d, 64); }
  __shared__ float a1[4], a2[4];
  const int wid = tid >> 6;
  if ((tid & 63) == 0) { a1[wid] = s1; a2[wid] = s2; }
  __syncthreads();
  s1 = a1[0] + a1[1] + a1[2] + a1[3];
  s2 = a2[0] + a2[1] + a2[2] + a2[3];
  const float mu = s1 * (1.f / 1024.f);
  const float rs = rsqrtf(s2 * (1.f / 1024.f) - mu * mu + 1e-5f);
  f32x4 gv = *(const f32x4*)&g[tid * 4];
  f32x4 bv = *(const f32x4*)&b[tid * 4];
#pragma unroll
  for (int j = 0; j < 4; ++j) v[j] = (v[j] - mu) * rs * gv[j] + bv[j];
  *(f32x4*)&h[row * 1024 + tid * 4] = v;
}

// ---------------------------------------------------------------------------
extern "C" void kernel_launch(void* const* d_in, const int* in_sizes, int n_in,
                              void* d_out, int out_size, void* d_ws, size_t ws_size,
                              hipStream_t stream)
{
  const float* x     = (const float*)d_in[0];
  const float* kbank = (const float*)d_in[1];
  const float* wq    = (const float*)d_in[2];
  const float* bq    = (const float*)d_in[3];
  const float* wk    = (const float*)d_in[4];
  const float* bk    = (const float*)d_in[5];
  const float* wv    = (const float*)d_in[6];
  const float* bv    = (const float*)d_in[7];
  const float* wf    = (const float*)d_in[8];
  const float* bf_   = (const float*)d_in[9];
  const float* gamma = (const float*)d_in[10];
  const float* beta  = (const float*)d_in[11];

  // ws layout (MB offsets):
  //   [0,32)   Qb bf16[16384,1024]  -> later aliased as Rb (retrieved)
  //   [32,48)  Kb bf16[8192,1024]
  //   [48,64)  Vt bf16[1024,8192]
  //   [64,+64K) L f32[16384]
  //   big path (ws >= 123 MB):
  //   [65,97)  xb   [97,113) bankb  [113,117) wfb  [117,119) wqb
  //   [119,121) wkb [121,123) wvb
  // P (bf16, 4096x8192 per chunk) lives in d_out (64 MB), dead until concat GEMM.
  char* ws = (char*)d_ws;
  const size_t MB = 1024 * 1024;
  bf16*  Qb    = (bf16*)ws;
  bf16*  Rb    = Qb;                       // alias: PV writes after S-exp reads
  bf16*  Kb    = (bf16*)(ws + 32 * MB);
  bf16*  Vt    = (bf16*)(ws + 48 * MB);
  float* L     = (float*)(ws + 64 * MB);
  bf16*  xb    = (bf16*)(ws + 65 * MB);
  bf16*  bankb = (bf16*)(ws + 97 * MB);
  bf16*  wfb   = (bf16*)(ws + 113 * MB);
  bf16*  wqb   = (bf16*)(ws + 117 * MB);
  bf16*  wkb   = (bf16*)(ws + 119 * MB);
  bf16*  wvb   = (bf16*)(ws + 121 * MB);
  bf16*  P     = (bf16*)d_out;
  float* out   = (float*)d_out;
  const bool big = ws_size >= 123 * MB;

  if (big) {
    cvt6<<<dim3(29696), dim3(256), 0, stream>>>(
        x, kbank, wq, wk, wv, wf, xb, bankb, wqb, wkb, wvb, wfb);
    gemm_bb<0,0><<<dim3(8, 128), dim3(256), 0, stream>>>(
        xb, nullptr, wqb, bq, nullptr, nullptr, (void*)Qb, 1024, 1024, 1024);
    gemm_bb<0,0><<<dim3(8, 64), dim3(256), 0, stream>>>(
        bankb, nullptr, wkb, bk, nullptr, nullptr, (void*)Kb, 1024, 1024, 1024);
    gemm_bb<1,0><<<dim3(64, 8), dim3(256), 0, stream>>>(
        wvb, nullptr, bankb, bv, nullptr, nullptr, (void*)Vt, 8192, 1024, 1024);
  } else {
    gemm_nt<0,0,0><<<dim3(8, 128), dim3(256), 0, stream>>>(
        x, nullptr, wq, bq, nullptr, (void*)Qb, 16384, 1024, 1024);
    gemm_nt<0,0,0><<<dim3(8, 64), dim3(256), 0, stream>>>(
        kbank, nullptr, wk, bk, nullptr, (void*)Kb, 8192, 1024, 1024);
    gemm_nt<1,0,0><<<dim3(64, 8), dim3(256), 0, stream>>>(
        wv, nullptr, kbank, bv, nullptr, (void*)Vt, 1024, 8192, 1024);
  }

  zerof<<<dim3(64), dim3(256), 0, stream>>>(L);
  for (int c = 0; c < 4; ++c) {
    // P = exp(Q_chunk Kb^T / 32) into d_out; rowsums -> L
    if (big)
      gemm_bb<2,0><<<dim3(64, 32), dim3(256), 0, stream>>>(
          Qb + (size_t)c * 4096 * 1024, nullptr, Kb, nullptr, nullptr,
          L + c * 4096, (void*)P, 8192, 1024, 1024);
    else
      gemm_bb<2,0><<<dim3(64, 32), dim3(256), 0, stream>>>(
          Qb + (size_t)c * 4096 * 1024, nullptr, Kb, nullptr, nullptr,
          L + c * 4096, (void*)P, 8192, 1024, 1024);
    // Rb_chunk = (P Vt^T) / L   (overwrites Qb chunk c, already consumed)
    pv_gemm<<<dim3(8, 32), dim3(512), 0, stream>>>(
        P, Vt, L + c * 4096, Rb + (size_t)c * 4096 * 1024);
  }

  // h = [x, retrieved] @ wf^T + bf + x -> d_out (fp32); P fully dead now
  if (big) {
    gemm_bb<3,1><<<dim3(8, 128), dim3(256), 0, stream>>>(
        xb, Rb, wfb, bf_, x, nullptr, (void*)out, 1024, 2048, 2048);
  } else {
    gemm_nt<0,1,1><<<dim3(8, 128), dim3(256), 0, stream>>>(
        x, Rb, wf, bf_, x, (void*)out, 16384, 1024, 2048);
  }
  ln_kernel<<<dim3(16384), dim3(256), 0, stream>>>(out, gamma, beta);
}

// Round 3
// 1018.234 us; speedup vs baseline: 1.1530x; 1.0675x over previous
//
#include <hip/hip_runtime.h>

// PersistentMemory: x[16384,1024], bank[8192,1024]; all fp32 in/out.
// Round 6: (a) XMAP=1 N-partitioned XCD mapping for the wide-N GEMMs (S-exp,
// Vt proj): each XCD owns an 8-column bn-slice so its B working set (2 MB)
// stays L2-resident; round-5 chunk mapping streamed all 16 MB of B through
// each 4 MB L2 (S-exp FETCH 245 MB vs 24 unique). (b) pv_gemm rebuilt as a
// BK=64 / 4-buffer / 3-deep-prefetch pipeline with counted vmcnt(8) + raw
// s_barrier (never vmcnt(0) in loop): __syncthreads() drains vmcnt, which
// defeated round-5's 2-phase dbuf.
// Base ws need: 64 MB + 64 KB. If ws >= 123 MB, inputs are pre-converted to
// bf16 and all GEMMs use the m97 global_load_lds structure (big path).

typedef __bf16 bf16;
typedef __bf16 bf16x4 __attribute__((ext_vector_type(4)));
typedef __bf16 bf16x8 __attribute__((ext_vector_type(8)));
typedef float f32x4 __attribute__((ext_vector_type(4)));

static __device__ __forceinline__ f32x4 mfma16(bf16x8 a, bf16x8 b, f32x4 c) {
  return __builtin_amdgcn_mfma_f32_16x16x32_bf16(a, b, c, 0, 0, 0);
}

// async global->LDS, 16B per lane; LDS dest = wave-uniform base + lane*16
#define GLDS16(gp, lp) __builtin_amdgcn_global_load_lds( \
    (const __attribute__((address_space(1))) void*)(gp), \
    (__attribute__((address_space(3))) void*)(lp), 16, 0, 0)

// ---------------------------------------------------------------------------
// bf16 NT-GEMM, m97 structure: C[M,N]=A[M,K]@W[N,K]^T (W row stride = ldw).
// 128x128 tile, BK=64, 256 thr = 4 waves (2x2, wave tile 64x64).
// XMAP 0: XCD-chunked flat swizzle (good when N-panels fit L2: Q/K/concat).
// XMAP 1: N partitioned across XCDs: XCD x owns bn in [x*nbxl, (x+1)*nbxl),
//         iterating by-major so its B-slice stays L2-resident (S-exp, Vt).
// EPI 0: C = bf16(acc + bias[col])                       (Q, K GEMMs)
// EPI 1: C = bf16(acc + bias[row])                       (Vt GEMM)
// EPI 2: C = bf16(exp(acc/32)), rowsum atomicAdd -> L    (S-exp)
// EPI 3: C = f32(acc + bias[col] + resid[row,col])       (concat GEMM)
// CONCAT: A columns >=1024 come from A2 (both stride 1024).
// ---------------------------------------------------------------------------
template<int EPI, int CONCAT, int XMAP>
__global__ __launch_bounds__(256, 3) void gemm_bb(
    const bf16* __restrict__ A, const bf16* __restrict__ A2,
    const bf16* __restrict__ W, const float* __restrict__ bias,
    const float* __restrict__ resid, float* __restrict__ L,
    void* __restrict__ Cout, int N, int K, int ldw)
{
  __shared__ bf16 As[128 * 64];
  __shared__ bf16 Bs[128 * 64];
  const int tid = threadIdx.x, lane = tid & 63, wid = tid >> 6;
  const int wm = (wid >> 1) * 64, wn = (wid & 1) * 64;
  const int quad = lane >> 4, l16 = lane & 15;
  long bm, bn;
  if (XMAP == 1) {
    // requires gridDim.x % 8 == 0; flat%8 is the XCD (dispatch round-robin)
    const int flat = (int)(blockIdx.y * gridDim.x + blockIdx.x);
    const int xcd = flat & 7;
    const int idx = flat >> 3;
    const int nbxl = (int)gridDim.x >> 3;
    const int byp = idx / nbxl;
    const int bxl = idx - byp * nbxl;
    bm = (long)byp * 128;
    bn = (long)(xcd * nbxl + bxl) * 128;
  } else {
    const int nwg = (int)(gridDim.x * gridDim.y);
    int flat = (int)(blockIdx.y * gridDim.x + blockIdx.x);
    flat = (flat & 7) * (nwg >> 3) + (flat >> 3);
    bm = (long)(flat / (int)gridDim.x) * 128;
    bn = (long)(flat % (int)gridDim.x) * 128;
  }

  int prow[4], pcg[4];
#pragma unroll
  for (int i = 0; i < 4; ++i) {
    int p = ((wid * 4 + i) << 6) + lane;   // 16B slot index in [0,1024)
    prow[i] = p >> 3;                      // 8 slots per 64-elem row
    pcg[i] = (p & 7) ^ (prow[i] & 7);
  }

  f32x4 acc[4][4] = {};

  for (int k0 = 0; k0 < K; k0 += 64) {
    const bf16* Asrc = (CONCAT && k0 >= 1024) ? A2 : A;
    const int kA = (CONCAT && k0 >= 1024) ? k0 - 1024 : k0;
    const int lda = CONCAT ? 1024 : K;
    __syncthreads();   // previous iteration's frag reads done before overwrite
#pragma unroll
    for (int i = 0; i < 4; ++i) {
      const bf16* ga = Asrc + (size_t)(bm + prow[i]) * lda + kA + pcg[i] * 8;
      GLDS16(ga, (char*)As + ((wid * 4 + i) << 10));
    }
#pragma unroll
    for (int i = 0; i < 4; ++i) {
      const bf16* gb = W + (size_t)(bn + prow[i]) * ldw + k0 + pcg[i] * 8;
      GLDS16(gb, (char*)Bs + ((wid * 4 + i) << 10));
    }
    __syncthreads();   // staging complete (vmcnt drained before barrier)
#pragma unroll
    for (int kk = 0; kk < 2; ++kk) {
      bf16x8 af[4], bfv[4];
#pragma unroll
      for (int mt = 0; mt < 4; ++mt) {
        const int r = wm + mt * 16 + l16;
        af[mt] = *(const bf16x8*)((const char*)As + (r << 7)
                                  + ((((kk << 2) + quad) ^ (r & 7)) << 4));
      }
#pragma unroll
      for (int nt = 0; nt < 4; ++nt) {
        const int r = wn + nt * 16 + l16;
        bfv[nt] = *(const bf16x8*)((const char*)Bs + (r << 7)
                                   + ((((kk << 2) + quad) ^ (r & 7)) << 4));
      }
#pragma unroll
      for (int mt = 0; mt < 4; ++mt)
#pragma unroll
        for (int nt = 0; nt < 4; ++nt)
          acc[mt][nt] = mfma16(af[mt], bfv[nt], acc[mt][nt]);
    }
  }

#pragma unroll
  for (int mt = 0; mt < 4; ++mt) {
    const long row0 = bm + wm + mt * 16 + quad * 4;
    if (EPI == 2) {
      float rsum[4] = {0.f, 0.f, 0.f, 0.f};
#pragma unroll
      for (int nt = 0; nt < 4; ++nt) {
        const long col = bn + wn + nt * 16 + l16;
#pragma unroll
        for (int r = 0; r < 4; ++r) {
          float p = __expf(acc[mt][nt][r] * 0.03125f);
          rsum[r] += p;
          ((bf16*)Cout)[(size_t)(row0 + r) * N + col] = (bf16)p;
        }
      }
#pragma unroll
      for (int s = 1; s < 16; s <<= 1)
#pragma unroll
        for (int r = 0; r < 4; ++r) rsum[r] += __shfl_xor(rsum[r], s, 64);
      if (l16 == 0) {
#pragma unroll
        for (int r = 0; r < 4; ++r) atomicAdd(&L[row0 + r], rsum[r]);
      }
    } else {
#pragma unroll
      for (int nt = 0; nt < 4; ++nt) {
        const long col = bn + wn + nt * 16 + l16;
        const float bc = (EPI == 1) ? 0.f : bias[col];
#pragma unroll
        for (int r = 0; r < 4; ++r) {
          float v = acc[mt][nt][r] + ((EPI == 1) ? bias[row0 + r] : bc);
          if (EPI == 3) {
            v += resid[(size_t)(row0 + r) * 1024 + col];
            ((float*)Cout)[(size_t)(row0 + r) * N + col] = v;
          } else {
            ((bf16*)Cout)[(size_t)(row0 + r) * N + col] = (bf16)v;
          }
        }
      }
    }
  }
}

// ---------------------------------------------------------------------------
// PV GEMM: Rb[4096,1024] = (P[4096,8192] @ Vt[1024,8192]^T) / L[row].
// 512 thr = 8 waves (4m x 2n, wave tile 32x64), 128x128 tile, BK=64.
// Grid 8x32 = 256 blocks = 1 block/CU (128 KB LDS) -> no inter-block overlap,
// so latency is hidden in-block: 4 LDS buffers, 3 K-steps prefetched, counted
// s_waitcnt vmcnt(8) (2 stages stay in flight) + raw s_barrier (one per iter,
// never vmcnt(0) in the main loop). setprio(1) around the MFMA cluster.
// ---------------------------------------------------------------------------
__global__ __launch_bounds__(512, 2) void pv_gemm(
    const bf16* __restrict__ P, const bf16* __restrict__ Vt,
    const float* __restrict__ L, bf16* __restrict__ Rb)
{
  __shared__ bf16 As[4][128 * 64];
  __shared__ bf16 Bs[4][128 * 64];
  const int tid = threadIdx.x, lane = tid & 63, wid = tid >> 6;
  const int wm = (wid & 3) * 32, wn = (wid >> 2) * 64;
  const int quad = lane >> 4, l16 = lane & 15;
  long bm, bn;
  {
    const int nwg = (int)(gridDim.x * gridDim.y);
    int flat = (int)(blockIdx.y * gridDim.x + blockIdx.x);
    flat = (flat & 7) * (nwg >> 3) + (flat >> 3);
    bm = (long)(flat / (int)gridDim.x) * 128;
    bn = (long)(flat % (int)gridDim.x) * 128;
  }

  int prow[2], pcg[2];
#pragma unroll
  for (int i = 0; i < 2; ++i) {
    int p = ((wid * 2 + i) << 6) + lane;   // 16B slot in [0,1024)
    prow[i] = p >> 3;                      // 8 slots per 64-elem row
    pcg[i] = (p & 7) ^ (prow[i] & 7);
  }

  f32x4 acc[2][4] = {};

  auto stage = [&](int buf, int k0) {
#pragma unroll
    for (int i = 0; i < 2; ++i)
      GLDS16(P + (size_t)(bm + prow[i]) * 8192 + k0 + pcg[i] * 8,
             (char*)As[buf] + ((wid * 2 + i) << 10));
#pragma unroll
    for (int i = 0; i < 2; ++i)
      GLDS16(Vt + (size_t)(bn + prow[i]) * 8192 + k0 + pcg[i] * 8,
             (char*)Bs[buf] + ((wid * 2 + i) << 10));
  };

  auto compute = [&](int buf) {
    __builtin_amdgcn_s_setprio(1);
#pragma unroll
    for (int kk = 0; kk < 2; ++kk) {
      bf16x8 af[2], bfv[4];
#pragma unroll
      for (int mt = 0; mt < 2; ++mt) {
        const int r = wm + mt * 16 + l16;
        af[mt] = *(const bf16x8*)((const char*)As[buf] + (r << 7)
                                  + ((((kk << 2) + quad) ^ (r & 7)) << 4));
      }
#pragma unroll
      for (int nt = 0; nt < 4; ++nt) {
        const int r = wn + nt * 16 + l16;
        bfv[nt] = *(const bf16x8*)((const char*)Bs[buf] + (r << 7)
                                   + ((((kk << 2) + quad) ^ (r & 7)) << 4));
      }
#pragma unroll
      for (int mt = 0; mt < 2; ++mt)
#pragma unroll
        for (int nt = 0; nt < 4; ++nt)
          acc[mt][nt] = mfma16(af[mt], bfv[nt], acc[mt][nt]);
    }
    __builtin_amdgcn_s_setprio(0);
  };

  // 128 K-steps of 64. Prologue: 3 stages in flight (12 loads).
  stage(0, 0);
  stage(1, 64);
  stage(2, 128);
  for (int t = 0; t < 126; ++t) {
    // wait until <=8 loads outstanding -> stage t landed; t+1,t+2 still fly
    asm volatile("s_waitcnt vmcnt(8)" ::: "memory");
    __builtin_amdgcn_s_barrier();       // raw: no implicit vmcnt(0) drain
    compute(t & 3);
    if (t < 125) stage((t + 3) & 3, (t + 3) * 64);
  }
  asm volatile("s_waitcnt vmcnt(4)" ::: "memory");
  __builtin_amdgcn_s_barrier();
  compute(126 & 3);
  asm volatile("s_waitcnt vmcnt(0)" ::: "memory");
  __builtin_amdgcn_s_barrier();
  compute(127 & 3);

#pragma unroll
  for (int mt = 0; mt < 2; ++mt) {
    const long row0 = bm + wm + mt * 16 + quad * 4;
    float linv[4];
#pragma unroll
    for (int r = 0; r < 4; ++r) linv[r] = 1.f / L[row0 + r];
#pragma unroll
    for (int nt = 0; nt < 4; ++nt) {
      const long col = bn + wn + nt * 16 + l16;
#pragma unroll
      for (int r = 0; r < 4; ++r)
        Rb[(size_t)(row0 + r) * 1024 + col] = (bf16)(acc[mt][nt][r] * linv[r]);
    }
  }
}

// ---------------------------------------------------------------------------
// fp32-input NT-GEMM (small-ws path only): C[M,N] = A[M,K] @ W[N,K]^T (+bias).
// ---------------------------------------------------------------------------
template<int BIAS_ROW, int OUT_F32_RES, int CONCAT>
__global__ __launch_bounds__(256, 3) void gemm_nt(
    const float* __restrict__ A, const bf16* __restrict__ A2,
    const float* __restrict__ W, const float* __restrict__ bias,
    const float* __restrict__ resid, void* __restrict__ Cout,
    int M, int N, int K)
{
  __shared__ bf16 As[128][72];
  __shared__ bf16 Bs[128][72];
  const int tid  = threadIdx.x;
  const int lane = tid & 63;
  const int wid  = tid >> 6;
  const int wm   = (wid >> 1) * 64, wn = (wid & 1) * 64;
  const int quad = lane >> 4, l16 = lane & 15;
  const long bm = (long)blockIdx.y * 128, bn = (long)blockIdx.x * 128;
  const int r0 = tid >> 2, cq = (tid & 3) * 16;
  const int lda = CONCAT ? 1024 : K;

  f32x4 acc[4][4] = {};

  for (int k0 = 0; k0 < K; k0 += 64) {
    const bool useb = CONCAT && (k0 >= 1024);
    const int kA = useb ? (k0 - 1024) : k0;
    f32x4 va[2][4], vb[2][4];
    bf16x8 ra[2][2];
    if (useb) {
#pragma unroll
      for (int g = 0; g < 2; ++g) {
        const bf16* p = A2 + (size_t)(bm + r0 + 64 * g) * 1024 + kA + cq;
        ra[g][0] = *(const bf16x8*)p;
        ra[g][1] = *(const bf16x8*)(p + 8);
      }
    } else {
#pragma unroll
      for (int g = 0; g < 2; ++g) {
        const f32x4* p = (const f32x4*)(A + (size_t)(bm + r0 + 64 * g) * lda + kA + cq);
#pragma unroll
        for (int j = 0; j < 4; ++j) va[g][j] = p[j];
      }
    }
#pragma unroll
    for (int g = 0; g < 2; ++g) {
      const f32x4* p = (const f32x4*)(W + (size_t)(bn + r0 + 64 * g) * K + k0 + cq);
#pragma unroll
      for (int j = 0; j < 4; ++j) vb[g][j] = p[j];
    }
    __syncthreads();
#pragma unroll
    for (int g = 0; g < 2; ++g) {
      bf16* dA = &As[r0 + 64 * g][cq];
      if (useb) {
        *(bf16x8*)dA = ra[g][0]; *(bf16x8*)(dA + 8) = ra[g][1];
      } else {
        bf16x8 t0, t1;
#pragma unroll
        for (int j = 0; j < 4; ++j) {
          t0[j] = (bf16)va[g][0][j]; t0[4 + j] = (bf16)va[g][1][j];
          t1[j] = (bf16)va[g][2][j]; t1[4 + j] = (bf16)va[g][3][j];
        }
        *(bf16x8*)dA = t0; *(bf16x8*)(dA + 8) = t1;
      }
      bf16* dB = &Bs[r0 + 64 * g][cq];
      bf16x8 u0, u1;
#pragma unroll
      for (int j = 0; j < 4; ++j) {
        u0[j] = (bf16)vb[g][0][j]; u0[4 + j] = (bf16)vb[g][1][j];
        u1[j] = (bf16)vb[g][2][j]; u1[4 + j] = (bf16)vb[g][3][j];
      }
      *(bf16x8*)dB = u0; *(bf16x8*)(dB + 8) = u1;
    }
    __syncthreads();
#pragma unroll
    for (int kk = 0; kk < 2; ++kk) {
      bf16x8 af[4], bfv[4];
#pragma unroll
      for (int mt = 0; mt < 4; ++mt)
        af[mt] = *(const bf16x8*)&As[wm + mt * 16 + l16][kk * 32 + quad * 8];
#pragma unroll
      for (int nt = 0; nt < 4; ++nt)
        bfv[nt] = *(const bf16x8*)&Bs[wn + nt * 16 + l16][kk * 32 + quad * 8];
#pragma unroll
      for (int mt = 0; mt < 4; ++mt)
#pragma unroll
        for (int nt = 0; nt < 4; ++nt)
          acc[mt][nt] = mfma16(af[mt], bfv[nt], acc[mt][nt]);
    }
  }
#pragma unroll
  for (int mt = 0; mt < 4; ++mt) {
    const long row0 = bm + wm + mt * 16 + quad * 4;
#pragma unroll
    for (int nt = 0; nt < 4; ++nt) {
      const long col = bn + wn + nt * 16 + l16;
      const float bc = BIAS_ROW ? 0.f : bias[col];
#pragma unroll
      for (int r = 0; r < 4; ++r) {
        float v = acc[mt][nt][r] + (BIAS_ROW ? bias[row0 + r] : bc);
        if (OUT_F32_RES) {
          v += resid[(size_t)(row0 + r) * 1024 + col];
          ((float*)Cout)[(size_t)(row0 + r) * N + col] = v;
        } else {
          ((bf16*)Cout)[(size_t)(row0 + r) * N + col] = (bf16)v;
        }
      }
    }
  }
}

// ---------------------------------------------------------------------------
// fp32 -> bf16 bulk convert of the six read-only inputs (big-ws path).
// One f32x4 per thread; segment bounds in float4 units.
// ---------------------------------------------------------------------------
__global__ __launch_bounds__(256) void cvt6(
    const float* __restrict__ x, const float* __restrict__ bank,
    const float* __restrict__ wq, const float* __restrict__ wk,
    const float* __restrict__ wv, const float* __restrict__ wf,
    bf16* __restrict__ xb, bf16* __restrict__ bankb,
    bf16* __restrict__ wqb, bf16* __restrict__ wkb,
    bf16* __restrict__ wvb, bf16* __restrict__ wfb)
{
  long i4 = (long)blockIdx.x * 256 + threadIdx.x;
  const float* src; bf16* dst; long off;
  if      (i4 < 4194304) { src = x;    dst = xb;    off = i4; }
  else if (i4 < 6291456) { src = bank; dst = bankb; off = i4 - 4194304; }
  else if (i4 < 6553600) { src = wq;   dst = wqb;   off = i4 - 6291456; }
  else if (i4 < 6815744) { src = wk;   dst = wkb;   off = i4 - 6553600; }
  else if (i4 < 7077888) { src = wv;   dst = wvb;   off = i4 - 6815744; }
  else if (i4 < 7602176) { src = wf;   dst = wfb;   off = i4 - 7077888; }
  else return;
  f32x4 v = ((const f32x4*)src)[off];
  bf16x4 o;
#pragma unroll
  for (int j = 0; j < 4; ++j) o[j] = (bf16)v[j];
  ((bf16x4*)dst)[off] = o;
}

__global__ __launch_bounds__(256) void zerof(float* __restrict__ p) {
  p[(size_t)blockIdx.x * 256 + threadIdx.x] = 0.f;
}

// ---------------------------------------------------------------------------
// In-place LayerNorm over last dim (1024). One block per row, 256 threads x4.
// ---------------------------------------------------------------------------
__global__ __launch_bounds__(256) void ln_kernel(
    float* __restrict__ h, const float* __restrict__ g, const float* __restrict__ b)
{
  const int tid = threadIdx.x;
  const size_t row = blockIdx.x;
  f32x4 v = *(f32x4*)&h[row * 1024 + tid * 4];
  float s1 = v[0] + v[1] + v[2] + v[3];
  float s2 = v[0]*v[0] + v[1]*v[1] + v[2]*v[2] + v[3]*v[3];
#pragma unroll
  for (int d = 1; d < 64; d <<= 1) { s1 += __shfl_xor(s1, d, 64); s2 += __shfl_xor(s2, d, 64); }
  __shared__ float a1[4], a2[4];
  const int wid = tid >> 6;
  if ((tid & 63) == 0) { a1[wid] = s1; a2[wid] = s2; }
  __syncthreads();
  s1 = a1[0] + a1[1] + a1[2] + a1[3];
  s2 = a2[0] + a2[1] + a2[2] + a2[3];
  const float mu = s1 * (1.f / 1024.f);
  const float rs = rsqrtf(s2 * (1.f / 1024.f) - mu * mu + 1e-5f);
  f32x4 gv = *(const f32x4*)&g[tid * 4];
  f32x4 bv = *(const f32x4*)&b[tid * 4];
#pragma unroll
  for (int j = 0; j < 4; ++j) v[j] = (v[j] - mu) * rs * gv[j] + bv[j];
  *(f32x4*)&h[row * 1024 + tid * 4] = v;
}

// ---------------------------------------------------------------------------
extern "C" void kernel_launch(void* const* d_in, const int* in_sizes, int n_in,
                              void* d_out, int out_size, void* d_ws, size_t ws_size,
                              hipStream_t stream)
{
  const float* x     = (const float*)d_in[0];
  const float* kbank = (const float*)d_in[1];
  const float* wq    = (const float*)d_in[2];
  const float* bq    = (const float*)d_in[3];
  const float* wk    = (const float*)d_in[4];
  const float* bk    = (const float*)d_in[5];
  const float* wv    = (const float*)d_in[6];
  const float* bv    = (const float*)d_in[7];
  const float* wf    = (const float*)d_in[8];
  const float* bf_   = (const float*)d_in[9];
  const float* gamma = (const float*)d_in[10];
  const float* beta  = (const float*)d_in[11];

  // ws layout (MB offsets):
  //   [0,32)   Qb bf16[16384,1024]  -> later aliased as Rb (retrieved)
  //   [32,48)  Kb bf16[8192,1024]
  //   [48,64)  Vt bf16[1024,8192]
  //   [64,+64K) L f32[16384]
  //   big path (ws >= 123 MB):
  //   [65,97)  xb   [97,113) bankb  [113,117) wfb  [117,119) wqb
  //   [119,121) wkb [121,123) wvb
  // P (bf16, 4096x8192 per chunk) lives in d_out (64 MB), dead until concat GEMM.
  char* ws = (char*)d_ws;
  const size_t MB = 1024 * 1024;
  bf16*  Qb    = (bf16*)ws;
  bf16*  Rb    = Qb;                       // alias: PV writes after S-exp reads
  bf16*  Kb    = (bf16*)(ws + 32 * MB);
  bf16*  Vt    = (bf16*)(ws + 48 * MB);
  float* L     = (float*)(ws + 64 * MB);
  bf16*  xb    = (bf16*)(ws + 65 * MB);
  bf16*  bankb = (bf16*)(ws + 97 * MB);
  bf16*  wfb   = (bf16*)(ws + 113 * MB);
  bf16*  wqb   = (bf16*)(ws + 117 * MB);
  bf16*  wkb   = (bf16*)(ws + 119 * MB);
  bf16*  wvb   = (bf16*)(ws + 121 * MB);
  bf16*  P     = (bf16*)d_out;
  float* out   = (float*)d_out;
  const bool big = ws_size >= 123 * MB;

  if (big) {
    cvt6<<<dim3(29696), dim3(256), 0, stream>>>(
        x, kbank, wq, wk, wv, wf, xb, bankb, wqb, wkb, wvb, wfb);
    gemm_bb<0,0,0><<<dim3(8, 128), dim3(256), 0, stream>>>(
        xb, nullptr, wqb, bq, nullptr, nullptr, (void*)Qb, 1024, 1024, 1024);
    gemm_bb<0,0,0><<<dim3(8, 64), dim3(256), 0, stream>>>(
        bankb, nullptr, wkb, bk, nullptr, nullptr, (void*)Kb, 1024, 1024, 1024);
    gemm_bb<1,0,1><<<dim3(64, 8), dim3(256), 0, stream>>>(
        wvb, nullptr, bankb, bv, nullptr, nullptr, (void*)Vt, 8192, 1024, 1024);
  } else {
    gemm_nt<0,0,0><<<dim3(8, 128), dim3(256), 0, stream>>>(
        x, nullptr, wq, bq, nullptr, (void*)Qb, 16384, 1024, 1024);
    gemm_nt<0,0,0><<<dim3(8, 64), dim3(256), 0, stream>>>(
        kbank, nullptr, wk, bk, nullptr, (void*)Kb, 8192, 1024, 1024);
    gemm_nt<1,0,0><<<dim3(64, 8), dim3(256), 0, stream>>>(
        wv, nullptr, kbank, bv, nullptr, (void*)Vt, 1024, 8192, 1024);
  }

  zerof<<<dim3(64), dim3(256), 0, stream>>>(L);
  for (int c = 0; c < 4; ++c) {
    // P = exp(Q_chunk Kb^T / 32) into d_out; rowsums -> L (XMAP=1: XCD-column)
    gemm_bb<2,0,1><<<dim3(64, 32), dim3(256), 0, stream>>>(
        Qb + (size_t)c * 4096 * 1024, nullptr, Kb, nullptr, nullptr,
        L + c * 4096, (void*)P, 8192, 1024, 1024);
    // Rb_chunk = (P Vt^T) / L   (overwrites Qb chunk c, already consumed)
    pv_gemm<<<dim3(8, 32), dim3(512), 0, stream>>>(
        P, Vt, L + c * 4096, Rb + (size_t)c * 4096 * 1024);
  }

  // h = [x, retrieved] @ wf^T + bf + x -> d_out (fp32); P fully dead now
  if (big) {
    gemm_bb<3,1,0><<<dim3(8, 128), dim3(256), 0, stream>>>(
        xb, Rb, wfb, bf_, x, nullptr, (void*)out, 1024, 2048, 2048);
  } else {
    gemm_nt<0,1,1><<<dim3(8, 128), dim3(256), 0, stream>>>(
        x, Rb, wf, bf_, x, (void*)out, 16384, 1024, 2048);
  }
  ln_kernel<<<dim3(16384), dim3(256), 0, stream>>>(out, gamma, beta);
}